// Round 8
// baseline (222.297 us; speedup 1.0000x reference)
//
#include <hip/hip_runtime.h>
#include <cstdint>
#include <cstddef>

// Problem constants (B=128, S=256, H=128, HEADS=8, STEP=1)
#define BB   128
#define SS   256
#define HH   128
#define NH   8
#define DKK  16

typedef unsigned short u16;
typedef __attribute__((ext_vector_type(8))) short   sh8;    // 8 bf16 = 4 VGPRs (MFMA A/B frag)
typedef __attribute__((ext_vector_type(4))) float   f32x4;  // MFMA C/D frag

__device__ __forceinline__ float sigmoidf_(float x) { return 1.f / (1.f + expf(-x)); }

__device__ __forceinline__ u16 f2bf(float x) {
    union { float f; unsigned int u; } v; v.f = x;
    unsigned int r = (v.u + 0x7fffu + ((v.u >> 16) & 1u)) >> 16;  // RNE (finite inputs)
    return (u16)r;
}
__device__ __forceinline__ float bf2f(u16 u) {
    union { unsigned int u; float f; } v; v.u = ((unsigned int)u) << 16;
    return v.f;
}
__device__ __forceinline__ float bflo(unsigned u) {
    union { unsigned u; float f; } v; v.u = u << 16; return v.f;
}
__device__ __forceinline__ float bfhi(unsigned u) {
    union { unsigned u; float f; } v; v.u = u & 0xffff0000u; return v.f;
}
__device__ __forceinline__ unsigned pack2(u16 lo, u16 hi) {
    return (unsigned)lo | ((unsigned)hi << 16);
}

// ---------------------------------------------------------------------------
// bf16 MFMA GEMM, 128x128 tile, BK=32, 256 threads = 4 waves, each wave 64x64
// (4x4 grid of 16x16x32 MFMA).  B operand is B^T layout [N][K] bf16.
// Software-pipelined via NAMED register vars + straight-line macros (round-5:
// lambda-captured prefetch -> alloca -> 156 MB scratch traffic regression).
// XMODE: 0 = bf16 [M][K]; 1 = fp32 [M][K] (cast while staging);
//        2 = K-concat: bf16 Xa for k<ksplit, bf16 Xc after.
// OMODE: 1 = bf16 row-major out;
//        3 = fused GRU epilogue (LDS-gather): W3 cols gate-interleaved
//            (n=4c+g, g:0=r 1=i 2=n 3=hn); adds rank-1 rs_in*u[n]+rs_out*v[n]
//            (the b_ein/b_eout fold from the eliminated E GEMM), then
//            hnew = h - sig(gi)*(h - tanh(i_n + sig(gr)*h_n)), bf16 stores.
// RS=1 (with XMODE=1): also emit rowsum(X) per row to rsbuf (fp32 staging
//            values summed — exact), for the gates rank-1 correction.
// Batch (grid.z): z -> zb=z>>1, zh=z&1; offsets = zb*s?b + zh*s?h.
// All dims are exact multiples of tile sizes — no bounds checks.
// ---------------------------------------------------------------------------
#define BKk 32
#define PK  40   // LDS K pitch in halves (32 + 8): conflict-free frag reads

template<int XMODE, int OMODE, int RS>
__global__ __launch_bounds__(256) void gemm_mfma(
    const void* __restrict__ Xa, const void* __restrict__ Xc, int ldx, int ldx1, int ksplit,
    long long sXb, long long sXh,
    const u16* __restrict__ Bw, int ldb, long long sBb, long long sBh,
    const float* __restrict__ bias,
    void* __restrict__ Out, long long ldo, long long sOb, long long sOh,
    int K, const u16* __restrict__ hid,
    float* __restrict__ rsbuf, const float* __restrict__ ubuf,
    const float* __restrict__ vbuf)
{
    __shared__ __align__(16) char smem[2 * 128 * PK * 2];  // 20480 B
    u16* As = (u16*)smem;
    u16* Bs = (u16*)(smem + 128 * PK * 2);

    const int t  = threadIdx.x;
    const int bm = blockIdx.x * 128;
    const int bn = blockIdx.y * 128;
    const long long zb = blockIdx.z >> 1, zh = blockIdx.z & 1;

    const u16* Bp = Bw + zb * sBb + zh * sBh;

    const int wave = t >> 6, lane = t & 63;
    const int wr = (wave >> 1) * 64, wc = (wave & 1) * 64;
    const int fm = lane & 15, fq = lane >> 4;

    f32x4 acc[4][4] = {};

    const int r0  = t >> 2, kk0 = (t & 3) * 8;  // bf16 staging: 8 halves (16B), 2 chunks
    const int r1  = t >> 3, kk1 = (t & 7) * 4;  // fp32 staging: 4 floats, 4 chunks

    // prefetch registers — named scalars only (keep them out of scratch!)
    uint4  px0, px1, pb0, pb1;
    float4 pf0, pf1, pf2, pf3;
    float rs0 = 0.f, rs1 = 0.f, rs2 = 0.f, rs3 = 0.f;  // rowsum partials (RS)

#define LOADX(K0)                                                                    \
    if (XMODE == 1) {                                                                \
        const float* Xf_ = (const float*)Xa + zb * sXb + zh * sXh;                   \
        const float* xp_ = Xf_ + (long long)(bm + r1) * ldx + (K0) + kk1;            \
        pf0 = *(const float4*)(xp_);                                                 \
        pf1 = *(const float4*)(xp_ + 32LL * ldx);                                    \
        pf2 = *(const float4*)(xp_ + 64LL * ldx);                                    \
        pf3 = *(const float4*)(xp_ + 96LL * ldx);                                    \
    } else if (XMODE == 2 && (K0) >= ksplit) {                                       \
        const u16* xp_ = (const u16*)Xc + (long long)(bm + r0) * ldx1                \
                         + ((K0) - ksplit) + kk0;                                    \
        px0 = *(const uint4*)(xp_);                                                  \
        px1 = *(const uint4*)(xp_ + 64LL * ldx1);                                    \
    } else {                                                                         \
        const u16* xp_ = (const u16*)Xa + (long long)(bm + r0) * ldx + (K0) + kk0;   \
        px0 = *(const uint4*)(xp_);                                                  \
        px1 = *(const uint4*)(xp_ + 64LL * ldx);                                     \
    }

#define LOADB(K0)                                                                    \
    {                                                                                \
        const u16* bp_ = Bp + (long long)(bn + r0) * ldb + (K0) + kk0;               \
        pb0 = *(const uint4*)(bp_);                                                  \
        pb1 = *(const uint4*)(bp_ + 64LL * ldb);                                     \
    }

    LOADX(0)
    LOADB(0)

    for (int k0 = 0; k0 < K; k0 += BKk) {
        // ---- commit prefetched tile to LDS ----
        if (XMODE == 1) {
            if (RS) {
                rs0 += pf0.x + pf0.y + pf0.z + pf0.w;
                rs1 += pf1.x + pf1.y + pf1.z + pf1.w;
                rs2 += pf2.x + pf2.y + pf2.z + pf2.w;
                rs3 += pf3.x + pf3.y + pf3.z + pf3.w;
            }
            ushort4 w0 = { f2bf(pf0.x), f2bf(pf0.y), f2bf(pf0.z), f2bf(pf0.w) };
            ushort4 w1 = { f2bf(pf1.x), f2bf(pf1.y), f2bf(pf1.z), f2bf(pf1.w) };
            ushort4 w2 = { f2bf(pf2.x), f2bf(pf2.y), f2bf(pf2.z), f2bf(pf2.w) };
            ushort4 w3 = { f2bf(pf3.x), f2bf(pf3.y), f2bf(pf3.z), f2bf(pf3.w) };
            *(ushort4*)&As[(r1     ) * PK + kk1] = w0;
            *(ushort4*)&As[(r1 + 32) * PK + kk1] = w1;
            *(ushort4*)&As[(r1 + 64) * PK + kk1] = w2;
            *(ushort4*)&As[(r1 + 96) * PK + kk1] = w3;
        } else {
            *(uint4*)&As[(r0     ) * PK + kk0] = px0;
            *(uint4*)&As[(r0 + 64) * PK + kk0] = px1;
        }
        *(uint4*)&Bs[(r0     ) * PK + kk0] = pb0;
        *(uint4*)&Bs[(r0 + 64) * PK + kk0] = pb1;
        __syncthreads();

        // ---- issue next-tile loads (hide HBM latency behind frag+MFMA) ----
        if (k0 + BKk < K) {
            LOADX(k0 + BKk)
            LOADB(k0 + BKk)
        }

        sh8 af[4], bfr[4];
        #pragma unroll
        for (int i = 0; i < 4; i++) af[i]  = *(const sh8*)&As[(wr + i * 16 + fm) * PK + fq * 8];
        #pragma unroll
        for (int j = 0; j < 4; j++) bfr[j] = *(const sh8*)&Bs[(wc + j * 16 + fm) * PK + fq * 8];
        #pragma unroll
        for (int i = 0; i < 4; i++)
            #pragma unroll
            for (int j = 0; j < 4; j++)
                acc[i][j] = __builtin_amdgcn_mfma_f32_16x16x32_bf16(af[i], bfr[j], acc[i][j], 0, 0, 0);
        __syncthreads();
    }
#undef LOADX
#undef LOADB

    // ---- rowsum reduction (RS): 8 threads/row partials -> rsbuf ----
    if (XMODE == 1 && RS) {
        float* rsl = (float*)smem;  // [128][8] fp32 (LDS free after K-loop)
        rsl[(r1     ) * 8 + (t & 7)] = rs0;
        rsl[(r1 + 32) * 8 + (t & 7)] = rs1;
        rsl[(r1 + 64) * 8 + (t & 7)] = rs2;
        rsl[(r1 + 96) * 8 + (t & 7)] = rs3;
        __syncthreads();
        if (t < 128) {
            float s = 0.f;
            #pragma unroll
            for (int i2 = 0; i2 < 8; i2++) s += rsl[t * 8 + i2];
            rsbuf[zh * 32768LL + zb * 256LL + bm + t] = s;
        }
    }

    if (OMODE == 1) {
        // ---- epilogue: C layout col=lane&15, row=(lane>>4)*4+reg ----
        #pragma unroll
        for (int j = 0; j < 4; j++) {
            const int col = bn + wc + j * 16 + fm;
            const float bj = bias ? bias[col] : 0.f;
            #pragma unroll
            for (int i = 0; i < 4; i++) {
                const int row0 = bm + wr + i * 16 + fq * 4;
                u16* O = (u16*)Out + zb * sOb + zh * sOh;
                #pragma unroll
                for (int r = 0; r < 4; r++)
                    O[(long long)(row0 + r) * ldo + col] = f2bf(acc[i][j][r] + bj);
            }
        }
    } else {
        // ---- OMODE == 3: fused GRU epilogue, LDS-gather + rank-1 terms ----
        float* g4s = (float*)smem;       // [32][132] fp32 = 16896 B (reuses As/Bs)
        const int chbase = bn >> 2;      // global channel base for this block
        const int s_t = t >> 3;          // 0..31 slab row
        const int cq  = t & 7;           // 0..7 channel quad
        const int ncol0 = bn + 16 * cq;  // gate-space col base for gather thread
        u16* O = (u16*)Out;
        const int sbase = (wr ? 16 : 0) + fq * 4;
        if (XMODE == 1 && RS) __syncthreads();  // rsl -> g4s reuse
        #pragma unroll
        for (int i = 0; i < 4; i++) {
            // scatter acc+bias into LDS (rows of both wave halves -> 32 slab rows)
            #pragma unroll
            for (int j = 0; j < 4; j++) {
                const int q = wc + j * 16 + fm;
                const float bj = bias[bn + q];
                #pragma unroll
                for (int r = 0; r < 4; r++)
                    g4s[(sbase + r) * 132 + q] = acc[i][j][r] + bj;
            }
            __syncthreads();
            // gather: 1 row x 4 channels per thread, contiguous b128 reads
            {
                const int grow = bm + i * 16 + (s_t < 16 ? s_t : s_t + 48);
                const float rin  = rsbuf[grow];
                const float rout = rsbuf[32768 + grow];
                const ushort4 hv = *(const ushort4*)&hid[(long long)grow * HH + chbase + 4 * cq];
                const float hvv[4] = { bf2f(hv.x), bf2f(hv.y), bf2f(hv.z), bf2f(hv.w) };
                ushort4 w;
                u16* wp = (u16*)&w;
                #pragma unroll
                for (int m = 0; m < 4; m++) {
                    f32x4 gv = *(const f32x4*)&g4s[s_t * 132 + 16 * cq + 4 * m];
                    const float4 um = *(const float4*)&ubuf[ncol0 + 4 * m];
                    const float4 vm = *(const float4*)&vbuf[ncol0 + 4 * m];
                    float g0 = gv[0] + rin * um.x + rout * vm.x;
                    float g1 = gv[1] + rin * um.y + rout * vm.y;
                    float g2 = gv[2] + rin * um.z + rout * vm.z;
                    float g3 = gv[3] + rin * um.w + rout * vm.w;
                    float rg = sigmoidf_(g0);
                    float ig = sigmoidf_(g1);
                    float ng = tanhf(g2 + rg * g3);
                    wp[m] = f2bf(hvv[m] - ig * (hvv[m] - ng));
                }
                *(ushort4*)&O[(long long)grow * ldo + chbase + 4 * cq] = w;
            }
            __syncthreads();
        }
    }
}

// ---------------------------------------------------------------------------
// Weight prep + hidden cast + per-batch h transpose (grid 4096x256).
//   h_bf  = bf16(hidden)                     [32768][128]
//   h_bfT = bf16(hidden) transposed per batch [128 b][128 c][256 j]
//   W3bf [512x384] gate-interleaved rows (np=4c+g, g:0=r 1=i 2=n 3=hn):
//     kk<128 : (Wih_in @ W_ein)[n', kk]   (0 for g==3)
//     128..256: (Wih_out @ W_eout)[n', kk-128] (0 for g==3)
//     256..384: w_hh part (g<2: w_hh[g*128+c]; g==2: 0; g==3: w_hh[256+c])
//   bias2[np] = gate bias + (b_iah|b_oah) fold through w_ih.
//   u[np] = Wih_in @ b_ein, v[np] = Wih_out @ b_eout  (rank-1 epilogue terms)
//   Wq12 [256x128] = [W_q1; W_q2], biasq12 = [b_q1|b_q2]
// ---------------------------------------------------------------------------
__global__ __launch_bounds__(256) void k_prepw(
    const float* __restrict__ hidden, u16* __restrict__ h_bf, u16* __restrict__ h_bfT,
    const float* __restrict__ w_ih, const float* __restrict__ w_hh,
    const float* __restrict__ b_ih, const float* __restrict__ b_hh,
    const float* __restrict__ b_iah, const float* __restrict__ b_oah,
    const float* __restrict__ W_ein, const float* __restrict__ b_ein,
    const float* __restrict__ W_eout, const float* __restrict__ b_eout,
    const float* __restrict__ W_q1, const float* __restrict__ b_q1,
    const float* __restrict__ W_q2, const float* __restrict__ b_q2,
    u16* __restrict__ W3bf, float* __restrict__ bias2,
    float* __restrict__ ubuf, float* __restrict__ vbuf,
    u16* __restrict__ Wq12, float* __restrict__ biasq12)
{
    int idx = blockIdx.x * 256 + threadIdx.x;  // 0 .. 1048575
    {   // hidden -> bf16, 4 elems/thread
        float4 v = ((const float4*)hidden)[idx];
        ushort4 w = { f2bf(v.x), f2bf(v.y), f2bf(v.z), f2bf(v.w) };
        ((ushort4*)h_bf)[idx] = w;
    }
    if (idx < 512 * 384) {
        int np = idx / 384, kk = idx % 384;
        int c = np >> 2, g = np & 3;
        float v = 0.f;
        if (kk >= 256) {
            if (g < 2)       v = w_hh[(g * 128 + c) * 128 + kk - 256];
            else if (g == 3) v = w_hh[(256 + c) * 128 + kk - 256];
        } else if (g != 3) {
            const int n2 = (g < 2) ? g * 128 + c : 256 + c;
            const int half = kk >> 7, dd = kk & 127;
            const float* wr_ = w_ih + n2 * 256 + half * 128;
            const float* we_ = half ? W_eout : W_ein;
            float s = 0.f;
            #pragma unroll 8
            for (int q = 0; q < 128; q++) s += wr_[q] * we_[q * 128 + dd];
            v = s;
        }
        W3bf[idx] = f2bf(v);
    }
    if (idx < 256 * 128) {
        int n = idx >> 7, k = idx & 127;
        Wq12[idx] = f2bf(n < 128 ? W_q1[n * 128 + k] : W_q2[(n - 128) * 128 + k]);
    }
    if (idx < 512) {
        int np = idx, c = np >> 2, g = np & 3;
        float s;
        if (g < 2)       s = b_ih[g * 128 + c] + b_hh[g * 128 + c];
        else if (g == 2) s = b_ih[256 + c];
        else             s = b_hh[256 + c];
        float uu = 0.f, vv = 0.f;
        if (g != 3) {
            const int n2 = (g < 2) ? g * 128 + c : 256 + c;
            for (int k = 0; k < 128; k++) {
                s  += w_ih[n2 * 256 + k] * b_iah[k] + w_ih[n2 * 256 + 128 + k] * b_oah[k];
                uu += w_ih[n2 * 256 + k] * b_ein[k];
                vv += w_ih[n2 * 256 + 128 + k] * b_eout[k];
            }
        }
        bias2[np] = s;
        ubuf[np] = uu;
        vbuf[np] = vv;
    }
    if (idx < 256) {
        biasq12[idx] = idx < 128 ? b_q1[idx] : b_q2[idx - 128];
    }
    // ---- h_bfT: blocks 0..511 each transpose a [64 j x 128 c] tile ----
    if (blockIdx.x < 512) {
        const int b = blockIdx.x >> 2, jc = blockIdx.x & 3;
        const int c = threadIdx.x >> 1, j0 = (threadIdx.x & 1) * 32;
        const float* src = hidden + ((size_t)b * 256 + jc * 64 + j0) * 128 + c;
        u16* dst = h_bfT + ((size_t)b * 128 + c) * 256 + jc * 64 + j0;
        #pragma unroll
        for (int g8 = 0; g8 < 4; g8++) {
            float a0 = src[(g8 * 8 + 0) * 128];
            float a1 = src[(g8 * 8 + 1) * 128];
            float a2 = src[(g8 * 8 + 2) * 128];
            float a3 = src[(g8 * 8 + 3) * 128];
            float a4 = src[(g8 * 8 + 4) * 128];
            float a5 = src[(g8 * 8 + 5) * 128];
            float a6 = src[(g8 * 8 + 6) * 128];
            float a7 = src[(g8 * 8 + 7) * 128];
            uint4 w;
            w.x = pack2(f2bf(a0), f2bf(a1));
            w.y = pack2(f2bf(a2), f2bf(a3));
            w.z = pack2(f2bf(a4), f2bf(a5));
            w.w = pack2(f2bf(a6), f2bf(a7));
            *(uint4*)(dst + g8 * 8) = w;
        }
    }
}

// ---------------------------------------------------------------------------
// Fused attention tail: one block per batch b, 1024 threads (16 waves).
// mask-sum -> last idx -> q0 -> sigmoid scores -> softmax_j -> softmax_h ->
// weighted q2 readout, out[b] scaled by nvalid.  q12 is bf16 [32768][256]
// (cols 0:128 = q1, 128:256 = q2).
// ---------------------------------------------------------------------------
__global__ __launch_bounds__(1024) void k_tail(
    const u16* __restrict__ hnew_bf, const int* __restrict__ mask,
    const u16* __restrict__ q12, const float* __restrict__ Wq0,
    const float* __restrict__ bq0, float* __restrict__ out)
{
    const int b = blockIdx.x, t = threadIdx.x;
    __shared__ float red[1024];
    __shared__ float hs[HH];
    __shared__ float q0s[HH];
    __shared__ float p_s[NH][SS];
    __shared__ float w_s[NH][SS];
    __shared__ int s_nv;

    // ---- mask sum / last index ----
    if (t < 256) red[t] = (float)mask[b * SS + t];
    __syncthreads();
    for (int off = 128; off > 0; off >>= 1) {
        if (t < off) red[t] += red[t + off];
        __syncthreads();
    }
    if (t == 0) s_nv = (int)red[0];
    __syncthreads();
    const int nv = s_nv;
    const int last = (nv - 1) & (SS - 1);

    if (t < HH) hs[t] = bf2f(hnew_bf[((size_t)b * SS + last) * HH + t]);
    __syncthreads();

    // ---- q0 = h_last @ Wq0^T + bq0: n = t&127, K split 8 ways ----
    {
        const int n = t & 127, kh = t >> 7;
        const float* w = Wq0 + (size_t)n * HH + kh * 16;
        const float* h = hs + kh * 16;
        float s = 0.f;
        #pragma unroll
        for (int k = 0; k < 16; k++) s += h[k] * w[k];
        red[t] = s;
    }
    __syncthreads();
    if (t < HH) {
        float s = bq0[t];
        #pragma unroll
        for (int kh = 0; kh < 8; kh++) s += red[kh * 128 + t];
        q0s[t] = s;
    }
    __syncthreads();

    // ---- scores: j = t>>2, q = t&3; thread computes heads 2q, 2q+1 ----
    {
        const int j = t >> 2, q = t & 3;
        const u16* q1r = q12 + ((size_t)b * SS + j) * 256 + q * 32;
        uint4 va = *(const uint4*)(q1r);
        uint4 vb = *(const uint4*)(q1r + 8);
        uint4 vc = *(const uint4*)(q1r + 16);
        uint4 vd = *(const uint4*)(q1r + 24);
        const float* qa = q0s + q * 32;
        float s0 = qa[0]  * bflo(va.x) + qa[1]  * bfhi(va.x)
                 + qa[2]  * bflo(va.y) + qa[3]  * bfhi(va.y)
                 + qa[4]  * bflo(va.z) + qa[5]  * bfhi(va.z)
                 + qa[6]  * bflo(va.w) + qa[7]  * bfhi(va.w)
                 + qa[8]  * bflo(vb.x) + qa[9]  * bfhi(vb.x)
                 + qa[10] * bflo(vb.y) + qa[11] * bfhi(vb.y)
                 + qa[12] * bflo(vb.z) + qa[13] * bfhi(vb.z)
                 + qa[14] * bflo(vb.w) + qa[15] * bfhi(vb.w);
        float s1 = qa[16] * bflo(vc.x) + qa[17] * bfhi(vc.x)
                 + qa[18] * bflo(vc.y) + qa[19] * bfhi(vc.y)
                 + qa[20] * bflo(vc.z) + qa[21] * bfhi(vc.z)
                 + qa[22] * bflo(vc.w) + qa[23] * bfhi(vc.w)
                 + qa[24] * bflo(vd.x) + qa[25] * bfhi(vd.x)
                 + qa[26] * bflo(vd.y) + qa[27] * bfhi(vd.y)
                 + qa[28] * bflo(vd.z) + qa[29] * bfhi(vd.z)
                 + qa[30] * bflo(vd.w) + qa[31] * bfhi(vd.w);
        p_s[2 * q][j]     = sigmoidf_(s0);
        p_s[2 * q + 1][j] = sigmoidf_(s1);
    }
    __syncthreads();

    // ---- softmax over j per head (threads 0..255: 32 lanes/head, 8 vals) ----
    if (t < 256) {
        const int h = t >> 5, l = t & 31;
        float v[8], m = -1e30f;
        #pragma unroll
        for (int u = 0; u < 8; u++) { v[u] = p_s[h][l * 8 + u]; m = fmaxf(m, v[u]); }
        #pragma unroll
        for (int msk = 1; msk < 32; msk <<= 1) m = fmaxf(m, __shfl_xor(m, msk, 32));
        float sum = 0.f;
        #pragma unroll
        for (int u = 0; u < 8; u++) { v[u] = expf(v[u] - m); sum += v[u]; }
        #pragma unroll
        for (int msk = 1; msk < 32; msk <<= 1) sum += __shfl_xor(sum, msk, 32);
        const float inv = 1.f / sum;
        #pragma unroll
        for (int u = 0; u < 8; u++) p_s[h][l * 8 + u] = v[u] * inv;
    }
    __syncthreads();

    // ---- head softmax per j (threads 0..255) ----
    if (t < 256) {
        float e[NH], den = 0.f;
        #pragma unroll
        for (int h = 0; h < NH; h++) { e[h] = expf(2.f * p_s[h][t]); den += e[h]; }
        const float inv = 1.f / den;
        #pragma unroll
        for (int h = 0; h < NH; h++) w_s[h][t] = e[h] * inv;
    }
    __syncthreads();

    // ---- readout: col = t&127, j split 8 ways; LDS cross-reduce ----
    {
        const int col = t & 127, jq = t >> 7;
        const int h = col >> 4;
        const u16* q2b = q12 + (size_t)b * SS * 256 + 128 + col;
        float acc = 0.f;
        #pragma unroll 4
        for (int j = jq * 32; j < jq * 32 + 32; j++)
            acc += w_s[h][j] * bf2f(q2b[(size_t)j * 256]);
        red[t] = acc;
    }
    __syncthreads();
    if (t < HH) {
        float s = 0.f;
        #pragma unroll
        for (int jq = 0; jq < 8; jq++) s += red[jq * 128 + t];
        out[(size_t)b * HH + t] = s * (float)nv;
    }
}

// ---------------------------------------------------------------------------
extern "C" void kernel_launch(void* const* d_in, const int* in_sizes, int n_in,
                              void* d_out, int out_size, void* d_ws, size_t ws_size,
                              hipStream_t stream)
{
    const float* A      = (const float*)d_in[0];
    const float* hidden = (const float*)d_in[1];
    const int*   mask   = (const int*)d_in[2];
    const float* w_ih   = (const float*)d_in[3];
    const float* w_hh   = (const float*)d_in[4];
    const float* b_ih   = (const float*)d_in[5];
    const float* b_hh   = (const float*)d_in[6];
    const float* b_iah  = (const float*)d_in[7];
    const float* b_oah  = (const float*)d_in[8];
    const float* W_ein  = (const float*)d_in[9];
    const float* b_ein  = (const float*)d_in[10];
    const float* W_eout = (const float*)d_in[11];
    const float* b_eout = (const float*)d_in[12];
    const float* W_q0   = (const float*)d_in[13];
    const float* b_q0   = (const float*)d_in[14];
    const float* W_q1   = (const float*)d_in[15];
    const float* b_q1   = (const float*)d_in[16];
    const float* W_q2   = (const float*)d_in[17];
    const float* b_q2   = (const float*)d_in[18];
    float* out = (float*)d_out;
    char* ws = (char*)d_ws;

    // --- workspace layout (bytes) ---
    u16*   Mbuf    = (u16*)(ws + 0);             // [32768][256] bf16 AH (in|out)
    u16*   q12bf   = (u16*)(ws + 0);             // aliases Mbuf (dead after gates)
    u16*   hnew_bf = (u16*)(ws + 16777216);      // [32768][128] bf16
    u16*   h_bf    = (u16*)(ws + 25165824);      // [32768][128] bf16
    u16*   h_bfT   = (u16*)(ws + 33554432);      // [128][128][256] bf16 (per-batch h^T)
    u16*   W3bf    = (u16*)(ws + 41943040);      // [512][384]
    u16*   Wq12    = (u16*)(ws + 42336256);      // [256][128]
    float* bias2   = (float*)(ws + 42401792);    // [512]
    float* ubuf    = (float*)(ws + 42403840);    // [512]
    float* vbuf    = (float*)(ws + 42405888);    // [512]
    float* biasq12 = (float*)(ws + 42407936);    // [256]
    float* rsg     = (float*)(ws + 42408960);    // [2][32768] fp32 rowsums of A halves

    // 1. weight prep (W3 = Wih@We fold, u, v) + hidden cast + h^T
    k_prepw<<<4096, 256, 0, stream>>>(hidden, h_bf, h_bfT,
                                      w_ih, w_hh, b_ih, b_hh, b_iah, b_oah,
                                      W_ein, b_ein, W_eout, b_eout,
                                      W_q1, b_q1, W_q2, b_q2,
                                      W3bf, bias2, ubuf, vbuf, Wq12, biasq12);

    // 2. AH = A_half[b] (fp32) @ h[b] -> Mbuf bf16 (+ rowsums of A -> rsg)
    gemm_mfma<1, 1, 1><<<dim3(2, 1, 256), 256, 0, stream>>>(
        A, nullptr, 512, 0, 0, 131072LL, 256LL,
        h_bfT, 256, 32768LL, 0LL, nullptr,
        Mbuf, 256, 65536LL, 128LL, SS, nullptr,
        rsg, nullptr, nullptr);

    // 3. gates = [Mbuf | h_bf] @ W3^T + bias2 + rs_in*u + rs_out*v,
    //    fused GRU epilogue -> hnew bf16
    gemm_mfma<2, 3, 0><<<dim3(256, 4, 1), 256, 0, stream>>>(
        Mbuf, h_bf, 256, HH, 256, 0, 0,
        W3bf, 384, 0, 0, bias2,
        hnew_bf, HH, 0, 0, 384, h_bf,
        rsg, ubuf, vbuf);

    // 4. q12 = hnew @ [W_q1;W_q2]^T + bias (bf16 out, aliases Mbuf region)
    gemm_mfma<0, 1, 0><<<dim3(256, 2, 1), 256, 0, stream>>>(
        hnew_bf, nullptr, HH, 0, 0, 0, 0,
        Wq12, HH, 0, 0, biasq12,
        q12bf, 256, 0, 0, HH, nullptr,
        nullptr, nullptr, nullptr);

    // 5. fused attention tail (1024 threads/block)
    k_tail<<<BB, 1024, 0, stream>>>(hnew_bf, mask, q12bf, W_q0, b_q0, out);
}